// Round 8
// baseline (686.130 us; speedup 1.0000x reference)
//
#include <hip/hip_runtime.h>
#include <cstdint>
#include <cstddef>

typedef unsigned long long u64;
typedef unsigned int u32;
typedef __attribute__((ext_vector_type(8))) short short8;
typedef __attribute__((ext_vector_type(4))) float f32x4;

#define NBOX 100800
#define CAND_CAP 4096

// ---------------- workspace layout (bytes) ----------------
#define OFF_WTH0 ((size_t)0)
#define OFF_WTH1 ((size_t)18874368)
#define OFF_WTH2 ((size_t)23592960)
#define OFF_WTL0 ((size_t)24772608)
#define OFF_WTL1 ((size_t)43646976)
#define OFF_WTL2 ((size_t)48365568)
#define OFF_Y0   ((size_t)49545216)
#define OFF_Y1   ((size_t)56098816)
#define OFF_Y2   ((size_t)69206016)
#define OFF_KEYS ((size_t)95420416)
#define OFF_HIST ((size_t)96226816)   // 262144 (aliased as selp[256] after select)
#define OFF_META ((size_t)96488960)   // 64
#define OFF_LOG  ((size_t)96489024)   // 100800*4 = 403200
#define OFF_CAND ((size_t)96892224)   // 32768
#define OFF_SEL  ((size_t)96924992)   // 1024
#define OFF_XTH0 ((size_t)96926016)
#define OFF_XTH1 ((size_t)100202816)
#define OFF_XTH2 ((size_t)106756416)
#define OFF_XTL0 ((size_t)119863616)
#define OFF_XTL1 ((size_t)123140416)
#define OFF_XTL2 ((size_t)129694016)
#define NEED_FULL ((size_t)142801216)
#define ZERO_U32  ((u32)166352)            // (262144+64+403200)/4, hist..logits

// weff/beff alias the head of y0 (weff dead before winner_gemm writes y0)
#define WEFF0_OFF (OFF_Y0)
#define WEFF1_OFF (OFF_Y0 + 110592)
#define WEFF2_OFF (OFF_Y0 + 165888)
#define BEFF_OFF  (OFF_Y0 + 193536)
#define WEFF_LEN  ((size_t)193600)

// ---------------- bf16 helpers (RNE, finite inputs) ----------------
__device__ __forceinline__ short f2bf(float f) {
    u32 u = __float_as_uint(f);
    u = (u + 0x7fffu + ((u >> 16) & 1u)) >> 16;
    return (short)u;
}
__device__ __forceinline__ float bf2f(short h) {
    return __uint_as_float(((u32)(unsigned short)h) << 16);
}

// ---- weight prep (merged 3 heads + workspace zeroing) ----
// Fragment-ordered layout: [my(co/128)][ch(ci/32)][tap(9)][m(128)][ci(32)]
// Blocks [0,163): zero hist+meta+logits. Then 4096 head0, 1024 head1, 256 head2.
__global__ __launch_bounds__(256) void prep_w_all(
    const float* __restrict__ w0, short* __restrict__ wh0, short* __restrict__ wl0,
    const float* __restrict__ w1, short* __restrict__ wh1, short* __restrict__ wl1,
    const float* __restrict__ w2, short* __restrict__ wh2, short* __restrict__ wl2,
    u32* __restrict__ zbase)
{
    u32 b = blockIdx.x;
    if (b < 163) {
        u32 i = (b * 256 + threadIdx.x) * 4;
        if (i + 4 <= ZERO_U32) {
            *(uint4*)(zbase + i) = make_uint4(0u, 0u, 0u, 0u);
        } else {
            for (u32 k = i; k < ZERO_U32; ++k) zbase[k] = 0u;
        }
        return;
    }
    b -= 163;
    const float* w; short* wh; short* wl; int C;
    if (b < 4096)      { w = w0; wh = wh0; wl = wl0; C = 1024; }
    else if (b < 5120) { b -= 4096; w = w1; wh = wh1; wl = wl1; C = 512; }
    else               { b -= 5120; w = w2; wh = wh2; wl = wl2; C = 256; }

    __shared__ float ws_[2304];
    int chunks256 = C >> 8;
    int co = (int)b / chunks256;
    int ci0 = ((int)b % chunks256) << 8;
    size_t base = ((size_t)co * C + ci0) * 9;
    for (int idx = threadIdx.x; idx < 2304; idx += 256) ws_[idx] = w[base + idx];
    __syncthreads();
    int my = co >> 7, m = co & 127;
    int chunksW = C >> 5;
    for (int idx = threadIdx.x; idx < 2304; idx += 256) {
        int tap = idx >> 8, ci = idx & 255;
        float v = ws_[ci * 9 + tap];
        short h = f2bf(v);
        short l = f2bf(v - bf2f(h));
        int gci = ci0 + ci;
        int ch = gci >> 5, ciw = gci & 31;
        size_t o = ((((size_t)my * chunksW + ch) * 9 + tap) * 128 + m) * 32 + ciw;
        wh[o] = h; wl[o] = l;
    }
}

// ---- weff: pre-contract objectness 1x1 into the 3x3 conv ----
// weff[a][tap][ci] = sum_co w1[(a*85+4)*C+co] * w3[co][ci][tap]
// beff[a] = sum_co w1obj[a][co] * b3[co]
// Grid 112: head0 16cib x 4 co-splits, head1 8x4, head2 4x4. atomicAdd partials
// (weff region pre-zeroed by memset).
__global__ __launch_bounds__(256) void weff_kernel(
    const float* __restrict__ w30, const float* __restrict__ w1o0, const float* __restrict__ b30,
    const float* __restrict__ w31, const float* __restrict__ w1o1, const float* __restrict__ b31,
    const float* __restrict__ w32, const float* __restrict__ w1o2, const float* __restrict__ b32,
    float* __restrict__ weff0, float* __restrict__ weff1, float* __restrict__ weff2,
    float* __restrict__ beff)
{
    u32 b = blockIdx.x;
    const float *w3, *w1, *b3; float* wf; int C, hidx;
    if (b < 64)      { w3 = w30; w1 = w1o0; b3 = b30; wf = weff0; C = 1024; hidx = 0; }
    else if (b < 96) { b -= 64; w3 = w31; w1 = w1o1; b3 = b31; wf = weff1; C = 512; hidx = 1; }
    else             { b -= 96; w3 = w32; w1 = w1o2; b3 = b32; wf = weff2; C = 256; hidx = 2; }
    int q = (int)b & 3, cib = (int)b >> 2;
    int ci0 = cib * 64;
    int cq = C >> 2, co0 = q * cq;

    __shared__ float lw1[3][256];
    for (int idx = threadIdx.x; idx < 3 * cq; idx += 256) {
        int a = idx / cq, j = idx - a * cq;
        lw1[a][j] = w1[(size_t)(a * 85 + 4) * C + co0 + j];
    }
    __syncthreads();

    int t = threadIdx.x;
    float acc[3][3] = {};   // [pair][anchor]
    for (int j = 0; j < cq; j++) {
        const float* row = w3 + ((size_t)(co0 + j) * C + ci0) * 9;
        float l0 = lw1[0][j], l1 = lw1[1][j], l2 = lw1[2][j];
        #pragma unroll
        for (int pp = 0; pp < 3; pp++) {
            int pi = t + pp * 256;
            if (pi < 576) {
                float v = row[pi];
                acc[pp][0] = fmaf(l0, v, acc[pp][0]);
                acc[pp][1] = fmaf(l1, v, acc[pp][1]);
                acc[pp][2] = fmaf(l2, v, acc[pp][2]);
            }
        }
    }
    #pragma unroll
    for (int pp = 0; pp < 3; pp++) {
        int pi = t + pp * 256;
        if (pi < 576) {
            int cil = pi / 9, tap = pi - cil * 9;
            #pragma unroll
            for (int a = 0; a < 3; a++)
                atomicAdd(&wf[(size_t)(a * 9 + tap) * C + ci0 + cil], acc[pp][a]);
        }
    }
    if (cib == 0) {
        __shared__ float red[256];
        for (int a = 0; a < 3; a++) {
            float s = 0.f;
            for (int j = t; j < cq; j += 256) s = fmaf(lw1[a][j], b3[co0 + j], s);
            red[t] = s; __syncthreads();
            for (int w = 128; w > 0; w >>= 1) { if (t < w) red[t] += red[t + w]; __syncthreads(); }
            if (t == 0) atomicAdd(&beff[hidx * 3 + a], red[0]);
            __syncthreads();
        }
    }
}

// ---------------- input prep: [C][HW] f32 -> [pix][C] bf16 hi/lo (transpose) --
struct PrepX { const float* x; short* xh; short* xl; int C, HW, bbase, ptiles; };

__global__ __launch_bounds__(256) void prep_x_kernel(PrepX p0, PrepX p1, PrepX p2)
{
    PrepX p = (blockIdx.x >= (u32)p2.bbase) ? p2 :
              (blockIdx.x >= (u32)p1.bbase) ? p1 : p0;
    int local = blockIdx.x - p.bbase;
    int pt = local % p.ptiles, ct = local / p.ptiles;
    __shared__ short th[32][34];
    __shared__ short tl[32][34];
    for (int idx = threadIdx.x; idx < 1024; idx += 256) {
        int ci = idx >> 5, px = idx & 31;
        float v = p.x[(size_t)(ct * 32 + ci) * p.HW + pt * 32 + px];
        short h = f2bf(v);
        th[ci][px] = h;
        tl[ci][px] = f2bf(v - bf2f(h));
    }
    __syncthreads();
    for (int idx = threadIdx.x; idx < 1024; idx += 256) {
        int px = idx >> 5, ci = idx & 31;
        size_t o = (size_t)(pt * 32 + px) * p.C + ct * 32 + ci;
        p.xh[o] = th[ci][px];
        p.xl[o] = tl[ci][px];
    }
}

// ---- obj conv: 3-out-channel 3x3 conv (fp32 VALU) -> logits atomicAdd ----
// Per head: pixel tiles of 256 x ci-splits of 32. Reads the f32 feats
// (L3-warm after prep_x). cib==0 seeds acc with beff.
struct ObjHead { const float* x; const float* wf; int C, H, W, HW, splits, lbase, bbase; };

__global__ __launch_bounds__(256) void obj_conv(
    ObjHead o0, ObjHead o1, ObjHead o2, const float* __restrict__ beff,
    float* __restrict__ logits)
{
    ObjHead oh; int hidx;
    if (blockIdx.x >= (u32)o2.bbase)      { oh = o2; hidx = 2; }
    else if (blockIdx.x >= (u32)o1.bbase) { oh = o1; hidx = 1; }
    else                                  { oh = o0; hidx = 0; }
    int local = blockIdx.x - oh.bbase;
    int cib = local % oh.splits;
    int pt  = local / oh.splits;
    int ci0 = cib * 32;

    __shared__ float wf[27][32];   // [a*9+tap][ci]
    for (int idx = threadIdx.x; idx < 864; idx += 256) {
        int at = idx >> 5, ci = idx & 31;
        wf[at][ci] = oh.wf[(size_t)at * oh.C + ci0 + ci];
    }
    __syncthreads();

    int p = pt * 256 + threadIdx.x;
    if (p >= oh.HW) return;
    int py = p / oh.W, px = p - py * oh.W;

    int xoff[9];
    #pragma unroll
    for (int t9 = 0; t9 < 9; t9++) {
        int dy = t9 / 3 - 1, dx = t9 % 3 - 1;
        int gy = py + dy, gx = px + dx;
        xoff[t9] = (gy >= 0 && gy < oh.H && gx >= 0 && gx < oh.W) ? (gy * oh.W + gx) : -1;
    }
    float a0, a1, a2;
    if (cib == 0) { a0 = beff[hidx*3]; a1 = beff[hidx*3+1]; a2 = beff[hidx*3+2]; }
    else          { a0 = a1 = a2 = 0.f; }
    const float* xr = oh.x + (size_t)ci0 * oh.HW;
    for (int ci = 0; ci < 32; ci++) {
        const float* xc = xr + (size_t)ci * oh.HW;
        #pragma unroll
        for (int t9 = 0; t9 < 9; t9++) {
            int o = xoff[t9];
            float xv = (o >= 0) ? xc[o] : 0.f;
            a0 = fmaf(wf[t9][ci],      xv, a0);
            a1 = fmaf(wf[9 + t9][ci],  xv, a1);
            a2 = fmaf(wf[18 + t9][ci], xv, a2);
        }
    }
    atomicAdd(&logits[oh.lbase + p], a0);
    atomicAdd(&logits[oh.lbase + oh.HW + p], a1);
    atomicAdd(&logits[oh.lbase + 2 * oh.HW + p], a2);
}

// ---------------- keys: logits -> sigmoid -> sort key + histogram ------------
__global__ __launch_bounds__(256) void keys_kernel(
    const float* __restrict__ logits,
    const float* __restrict__ b10, const float* __restrict__ b11, const float* __restrict__ b12,
    u64* __restrict__ keys, u32* __restrict__ hist)
{
    int i = blockIdx.x * 256 + threadIdx.x;
    if (i >= NBOX) return;
    float bias;
    if (i < 4800)       bias = b10[(i / 1600) * 85 + 4];
    else if (i < 24000) bias = b11[((i - 4800) / 6400) * 85 + 4];
    else                bias = b12[((i - 24000) / 25600) * 85 + 4];
    float s = 1.0f / (1.0f + expf(-(logits[i] + bias)));
    u64 k = ((u64)__float_as_uint(s) << 32) | (u64)(0xFFFFFFFFu - (u32)i);
    keys[i] = k;
    atomicAdd(&hist[(u32)(k >> 48)], 1u);
}

// ---------------- top-256 selection ----------------
__global__ __launch_bounds__(256) void select_kernel(const u32* __restrict__ hist,
                                                     u32* __restrict__ meta)
{
    __shared__ u32 csum[256];
    int t = threadIdx.x;
    const uint4* h4 = (const uint4*)(hist + t * 256);
    u32 s = 0;
    #pragma unroll 8
    for (int i = 0; i < 64; i++) { uint4 v = h4[i]; s += v.x + v.y + v.z + v.w; }
    csum[t] = s;
    __syncthreads();
    if (t == 0) {
        u32 cum = 0; int chunk = 255;
        for (; chunk > 0; chunk--) {
            if (cum + csum[chunk] >= 256u) break;
            cum += csum[chunk];
        }
        int B = chunk * 256;
        u32 cumAbove = cum;
        for (int bb = chunk * 256 + 255; bb >= chunk * 256; bb--) {
            u32 h = hist[bb];
            if (cumAbove + h >= 256u) { B = bb; break; }
            cumAbove += h;
        }
        meta[0] = (u32)B;
        meta[1] = cumAbove;
    }
}

__global__ __launch_bounds__(256) void compact_kernel(
    const u64* __restrict__ keys, int n, const u32* __restrict__ meta,
    u64* __restrict__ cand, u32* __restrict__ count)
{
    int i = blockIdx.x * blockDim.x + threadIdx.x;
    if (i < n) {
        u64 k = keys[i];
        if ((u32)(k >> 48) >= meta[0]) {
            u32 pos = atomicAdd(count, 1u);
            if (pos < CAND_CAP) cand[pos] = k;
        }
    }
}

// Dynamic bitonic sort + NEW: head-partition epilogue (selp + counts) for the
// winner GEMM (groups must be head-uniform). selp aliases the dead hist region.
__global__ __launch_bounds__(1024) void sort_select_kernel(
    const u64* __restrict__ cand, const u32* __restrict__ meta,
    u32* __restrict__ sel, u32* __restrict__ selp, u32* __restrict__ cnts)
{
    __shared__ u64 sk[CAND_CAP];
    __shared__ u32 selw[256];
    __shared__ unsigned char hh[256];
    int n = (int)meta[2];
    if (n > CAND_CAP) n = CAND_CAP;
    int P = 256;
    while (P < n) P <<= 1;          // 256 <= P <= 4096, uniform across block
    for (int i = threadIdx.x; i < P; i += 1024)
        sk[i] = (i < n) ? cand[i] : 0ull;
    __syncthreads();
    for (int k = 2; k <= P; k <<= 1) {
        for (int j = k >> 1; j > 0; j >>= 1) {
            for (int i = threadIdx.x; i < P; i += 1024) {
                int ixj = i ^ j;
                if (ixj > i) {
                    u64 a = sk[i], c = sk[ixj];
                    bool sw = ((i & k) == 0) ? (a > c) : (a < c);
                    if (sw) { sk[i] = c; sk[ixj] = a; }
                }
            }
            __syncthreads();
        }
    }
    if (threadIdx.x < 256) {
        u64 k = sk[P - 1 - threadIdx.x];
        u32 bi = 0xFFFFFFFFu - (u32)(k & 0xFFFFFFFFull);
        sel[threadIdx.x] = bi;
        selw[threadIdx.x] = bi;
        hh[threadIdx.x] = bi < 4800u ? 0 : (bi < 24000u ? 1 : 2);
    }
    __syncthreads();
    if (threadIdx.x < 256) {
        int h = hh[threadIdx.x];
        int rank = 0, n0 = 0, n1 = 0;
        for (int j = 0; j < 256; j++) {
            int hj = hh[j];
            if (j < (int)threadIdx.x && hj == h) rank++;
            if (hj == 0) n0++; else if (hj == 1) n1++;
        }
        int base = (h == 0) ? 0 : (h == 1) ? n0 : n0 + n1;
        selp[base + rank] = selw[threadIdx.x];
        if (threadIdx.x == 0) { cnts[0] = (u32)n0; cnts[1] = (u32)n1; }
    }
}

// ---- winner GEMM: full C-channel 3x3 conv at the <=256 winner pixels only --
// Blocks: 18 groups x 8 co-tiles. Group = 16 same-head winners (padded).
// 4 waves x 2 co-frags; MFMA 16x16x32 bf16 hi/lo 3-pass (same precision as
// the old full conv). A streams the fragment-ordered weights; B gathers
// winner hoods from xt ([pix][C], 16B/lane coalesced). Writes y[co][p]+bias
// so final_kernel is unchanged. Same-pixel dupes write identical values.
struct WinHead {
    const short* wh; const short* wl; const short* xh; const short* xl;
    const float* xf; const float* bias; float* y;
    int C, H, W, HW, mycnt, hbase;
};

__global__ __launch_bounds__(256) void winner_gemm(
    WinHead g0, WinHead g1, WinHead g2,
    const u32* __restrict__ selp, const u32* __restrict__ cnts, int use_xt)
{
    const u32 c0 = cnts[0], c1 = cnts[1];
    const u32 c2 = 256u - c0 - c1;
    const int ng0 = (int)((c0 + 15) >> 4), ng1 = (int)((c1 + 15) >> 4), ng2 = (int)((c2 + 15) >> 4);
    const int grpIdx = blockIdx.x >> 3;
    const int my = blockIdx.x & 7;
    WinHead g; int gl, spbase; u32 hcnt;
    if (grpIdx < ng0)            { gl = grpIdx;            g = g0; spbase = gl * 16;                 hcnt = c0; }
    else if (grpIdx < ng0 + ng1) { gl = grpIdx - ng0;      g = g1; spbase = (int)c0 + gl * 16;       hcnt = c1; }
    else { gl = grpIdx - ng0 - ng1; if (gl >= ng2) return; g = g2; spbase = (int)(c0 + c1) + gl * 16; hcnt = c2; }
    if (my >= g.mycnt) return;
    const int vcnt = min(16, (int)hcnt - gl * 16);

    const int tid = threadIdx.x;
    const int lane = tid & 63;
    const int wave = tid >> 6;
    const int quad = lane >> 4;
    const int l15 = lane & 15;

    __shared__ int o_lds[16][9];
    __shared__ int p_lds[16];
    if (tid < 144) {
        int n = tid / 9, tap = tid - n * 9;
        int o = -1, p = 0;
        if (n < vcnt) {
            u32 bi = selp[spbase + n];
            int r = (int)bi - g.hbase;
            p = r % g.HW;
            int py = p / g.W, px = p - py * g.W;
            int dy = tap / 3 - 1, dx = tap % 3 - 1;
            int gy = py + dy, gx = px + dx;
            if (gy >= 0 && gy < g.H && gx >= 0 && gx < g.W) o = gy * g.W + gx;
        }
        o_lds[n][tap] = o;
        if (tap == 0) p_lds[n] = (n < vcnt) ? p : -1;
    }
    __syncthreads();
    int otap[9];
    #pragma unroll
    for (int t9 = 0; t9 < 9; t9++) otap[t9] = o_lds[l15][t9];
    const int pn = p_lds[l15];

    const int chunks = g.C >> 5;
    const int f0 = wave * 2;
    const size_t abase = (size_t)my * chunks * 9 * 4096 + f0 * 512 + l15 * 32 + quad * 8;
    const short* __restrict__ wAh = g.wh + abase;
    const short* __restrict__ wAl = g.wl + abase;

    f32x4 acc0 = (f32x4){0.f,0.f,0.f,0.f}, acc1 = (f32x4){0.f,0.f,0.f,0.f};
    for (int ch = 0; ch < chunks; ++ch) {
        const int ci0 = ch << 5;
        #pragma unroll
        for (int tap = 0; tap < 9; ++tap) {
            size_t soff = ((size_t)ch * 9 + tap) * 4096;
            short8 a0h = *(const short8*)(wAh + soff);
            short8 a1h = *(const short8*)(wAh + soff + 512);
            short8 a0l = *(const short8*)(wAl + soff);
            short8 a1l = *(const short8*)(wAl + soff + 512);
            short8 bh = (short8){0,0,0,0,0,0,0,0};
            short8 bl = (short8){0,0,0,0,0,0,0,0};
            int o = otap[tap];
            if (o >= 0) {
                if (use_xt) {
                    size_t ro = (size_t)o * g.C + ci0 + quad * 8;
                    bh = *(const short8*)(g.xh + ro);
                    bl = *(const short8*)(g.xl + ro);
                } else {
                    #pragma unroll
                    for (int k = 0; k < 8; k++) {
                        float xv = g.xf[(size_t)(ci0 + quad * 8 + k) * g.HW + o];
                        short hh2 = f2bf(xv);
                        bh[k] = hh2; bl[k] = f2bf(xv - bf2f(hh2));
                    }
                }
            }
            acc0 = __builtin_amdgcn_mfma_f32_16x16x32_bf16(a0h, bh, acc0, 0, 0, 0);
            acc1 = __builtin_amdgcn_mfma_f32_16x16x32_bf16(a1h, bh, acc1, 0, 0, 0);
            acc0 = __builtin_amdgcn_mfma_f32_16x16x32_bf16(a0l, bh, acc0, 0, 0, 0);
            acc1 = __builtin_amdgcn_mfma_f32_16x16x32_bf16(a1l, bh, acc1, 0, 0, 0);
            acc0 = __builtin_amdgcn_mfma_f32_16x16x32_bf16(a0h, bl, acc0, 0, 0, 0);
            acc1 = __builtin_amdgcn_mfma_f32_16x16x32_bf16(a1h, bl, acc1, 0, 0, 0);
        }
    }
    if (pn >= 0) {
        #pragma unroll
        for (int r = 0; r < 4; r++) {
            int coA = my * 128 + f0 * 16 + quad * 4 + r;
            g.y[(size_t)coA * g.HW + pn] = acc0[r] + g.bias[coA];
            int coB = coA + 16;
            g.y[(size_t)coB * g.HW + pn] = acc1[r] + g.bias[coB];
        }
    }
}

// ---------------- final: full 85-ch 1x1 conv + decode for the 256 winners ---
__global__ __launch_bounds__(256) void final_kernel(
    const float* __restrict__ y0, const float* __restrict__ y1, const float* __restrict__ y2,
    const float* __restrict__ w10, const float* __restrict__ w11, const float* __restrict__ w12,
    const float* __restrict__ b10, const float* __restrict__ b11, const float* __restrict__ b12,
    const u32* __restrict__ sel, float* __restrict__ out)
{
    int b = blockIdx.x;
    u32 bi = sel[b];
    const float *y, *w1, *b1;
    int C, H, W, base; float ratio;
    float anchs[6];
    if (bi < 4800u) {
        y = y0; w1 = w10; b1 = b10; C = 1024; H = 40; W = 40; base = 0; ratio = 32.f;
        anchs[0]=116.f; anchs[1]=90.f; anchs[2]=156.f; anchs[3]=198.f; anchs[4]=373.f; anchs[5]=326.f;
    } else if (bi < 24000u) {
        y = y1; w1 = w11; b1 = b11; C = 512; H = 80; W = 80; base = 4800; ratio = 16.f;
        anchs[0]=30.f; anchs[1]=61.f; anchs[2]=62.f; anchs[3]=45.f; anchs[4]=59.f; anchs[5]=119.f;
    } else {
        y = y2; w1 = w12; b1 = b12; C = 256; H = 160; W = 160; base = 24000; ratio = 8.f;
        anchs[0]=10.f; anchs[1]=13.f; anchs[2]=16.f; anchs[3]=30.f; anchs[4]=33.f; anchs[5]=23.f;
    }
    int HW = H * W;
    int r = (int)bi - base;
    int a = r / HW, p = r % HW;
    __shared__ float ys[256];
    int c = threadIdx.x;
    float acc = 0.f;
    const float* wrow = w1 + (size_t)(a * 85 + (c < 85 ? c : 0)) * C;
    for (int ci0 = 0; ci0 < C; ci0 += 256) {
        __syncthreads();
        ys[c] = y[(size_t)(ci0 + c) * HW + p];
        __syncthreads();
        if (c < 85)
            for (int ci = 0; ci < 256; ci++) acc = fmaf(ys[ci], wrow[ci0 + ci], acc);
    }
    if (c < 85) {
        float v = acc + b1[a * 85 + c];
        float s = 1.0f / (1.0f + expf(-v));
        int py = p / W, px = p - (p / W) * W;
        float o;
        if (c == 0)      o = (s * 2.0f - 0.5f + (float)px) * ratio;
        else if (c == 1) o = (s * 2.0f - 0.5f + (float)py) * ratio;
        else if (c == 2) { float t = s * 2.0f; o = t * t * anchs[a * 2]; }
        else if (c == 3) { float t = s * 2.0f; o = t * t * anchs[a * 2 + 1]; }
        else             o = s;
        out[(size_t)b * 85 + c] = o;
    }
}

// ---------------- launch ----------------
extern "C" void kernel_launch(void* const* d_in, const int* in_sizes, int n_in,
                              void* d_out, int out_size, void* d_ws, size_t ws_size,
                              hipStream_t stream)
{
    const float* feat0 = (const float*)d_in[0];   // (256,160,160)
    const float* feat1 = (const float*)d_in[1];   // (512,80,80)
    const float* feat2 = (const float*)d_in[2];   // (1024,40,40)
    const float* w3_0 = (const float*)d_in[3];  const float* b3_0 = (const float*)d_in[4];
    const float* w1_0 = (const float*)d_in[5];  const float* b1_0 = (const float*)d_in[6];
    const float* w3_1 = (const float*)d_in[7];  const float* b3_1 = (const float*)d_in[8];
    const float* w1_1 = (const float*)d_in[9];  const float* b1_1 = (const float*)d_in[10];
    const float* w3_2 = (const float*)d_in[11]; const float* b3_2 = (const float*)d_in[12];
    const float* w1_2 = (const float*)d_in[13]; const float* b1_2 = (const float*)d_in[14];

    char* ws = (char*)d_ws;
    short* wth0 = (short*)(ws + OFF_WTH0);
    short* wth1 = (short*)(ws + OFF_WTH1);
    short* wth2 = (short*)(ws + OFF_WTH2);
    short* wtl0 = (short*)(ws + OFF_WTL0);
    short* wtl1 = (short*)(ws + OFF_WTL1);
    short* wtl2 = (short*)(ws + OFF_WTL2);
    float* y0   = (float*)(ws + OFF_Y0);
    float* y1   = (float*)(ws + OFF_Y1);
    float* y2   = (float*)(ws + OFF_Y2);
    u64*   keys = (u64*)  (ws + OFF_KEYS);
    u32*   hist = (u32*)  (ws + OFF_HIST);
    u32*   meta = (u32*)  (ws + OFF_META);
    float* logits = (float*)(ws + OFF_LOG);
    u64*   cand = (u64*)  (ws + OFF_CAND);
    u32*   sel  = (u32*)  (ws + OFF_SEL);
    float* weff0 = (float*)(ws + WEFF0_OFF);
    float* weff1 = (float*)(ws + WEFF1_OFF);
    float* weff2 = (float*)(ws + WEFF2_OFF);
    float* beff  = (float*)(ws + BEFF_OFF);

    const int use_xt = (ws_size >= NEED_FULL) ? 1 : 0;
    short* xth0 = (short*)(ws + OFF_XTH0);
    short* xth1 = (short*)(ws + OFF_XTH1);
    short* xth2 = (short*)(ws + OFF_XTH2);
    short* xtl0 = (short*)(ws + OFF_XTL0);
    short* xtl1 = (short*)(ws + OFF_XTL1);
    short* xtl2 = (short*)(ws + OFF_XTL2);

    // weff/beff zero (aliases head of y0; dead before winner_gemm writes y0)
    hipMemsetAsync(ws + OFF_Y0, 0, WEFF_LEN, stream);

    // weight transforms (fragment-ordered) + hist/meta/logits zeroing
    prep_w_all<<<163 + 4096 + 1024 + 256, 256, 0, stream>>>(
        w3_0, wth0, wtl0, w3_1, wth1, wtl1, w3_2, wth2, wtl2, (u32*)(ws + OFF_HIST));

    // objectness weight pre-contraction
    weff_kernel<<<112, 256, 0, stream>>>(w3_0, w1_0, b3_0, w3_1, w1_1, b3_1,
                                         w3_2, w1_2, b3_2, weff0, weff1, weff2, beff);

    // input transpose + bf16 split (feeds winner_gemm B gathers)
    if (use_xt) {
        PrepX p0 = {feat2, xth0, xtl0, 1024, 1600,  0,    50};
        PrepX p1 = {feat1, xth1, xtl1, 512,  6400,  1600, 200};
        PrepX p2 = {feat0, xth2, xtl2, 256,  25600, 4800, 800};
        prep_x_kernel<<<11200, 256, 0, stream>>>(p0, p1, p2);
    }

    // objectness logits for all boxes (3-channel conv, fp32)
    ObjHead o0 = {feat2, weff0, 1024, 40,  40,  1600,  32, 0,     0};
    ObjHead o1 = {feat1, weff1, 512,  80,  80,  6400,  16, 4800,  224};
    ObjHead o2 = {feat0, weff2, 256,  160, 160, 25600, 8,  24000, 624};
    obj_conv<<<1424, 256, 0, stream>>>(o0, o1, o2, beff, logits);

    // keys + histogram from logits
    keys_kernel<<<(NBOX + 255) / 256, 256, 0, stream>>>(logits, b1_0, b1_1, b1_2, keys, hist);

    // top-256
    select_kernel<<<1, 256, 0, stream>>>(hist, meta);
    compact_kernel<<<(NBOX + 255) / 256, 256, 0, stream>>>(keys, NBOX, meta, cand, meta + 2);
    sort_select_kernel<<<1, 1024, 0, stream>>>(cand, meta, sel, (u32*)(ws + OFF_HIST), meta + 4);

    // full-C conv at winner pixels only (writes y for final_kernel)
    WinHead g0 = {wth0, wtl0, xth0, xtl0, feat2, b3_0, y0, 1024, 40,  40,  1600,  8, 0};
    WinHead g1 = {wth1, wtl1, xth1, xtl1, feat1, b3_1, y1, 512,  80,  80,  6400,  4, 4800};
    WinHead g2 = {wth2, wtl2, xth2, xtl2, feat0, b3_2, y2, 256,  160, 160, 25600, 2, 24000};
    winner_gemm<<<144, 256, 0, stream>>>(g0, g1, g2, (u32*)(ws + OFF_HIST), meta + 4, use_xt);

    // full 85-channel compute + decode for winners only
    final_kernel<<<256, 256, 0, stream>>>(y0, y1, y2, w1_0, w1_1, w1_2,
                                          b1_0, b1_1, b1_2, sel, (float*)d_out);
}

// Round 9
// 482.429 us; speedup vs baseline: 1.4222x; 1.4222x over previous
//
#include <hip/hip_runtime.h>
#include <cstdint>
#include <cstddef>

typedef unsigned long long u64;
typedef unsigned int u32;
typedef __attribute__((ext_vector_type(8))) short short8;
typedef __attribute__((ext_vector_type(4))) float f32x4;

#define NBOX 100800
#define CAND_CAP 4096

// ---------------- workspace layout (bytes) ----------------
#define OFF_WTH0 ((size_t)0)
#define OFF_WTH1 ((size_t)18874368)
#define OFF_WTH2 ((size_t)23592960)
#define OFF_WTL0 ((size_t)24772608)
#define OFF_WTL1 ((size_t)43646976)
#define OFF_WTL2 ((size_t)48365568)
#define OFF_Y0   ((size_t)49545216)
#define OFF_Y1   ((size_t)56098816)
#define OFF_Y2   ((size_t)69206016)
#define OFF_KEYS ((size_t)95420416)
#define OFF_HIST ((size_t)96226816)   // 262144 (aliased: selp[256], selr[256] after select)
#define OFF_META ((size_t)96488960)   // 64
#define OFF_LOG  ((size_t)96489024)   // 100800*4 = 403200
#define OFF_CAND ((size_t)96892224)   // 32768
#define OFF_SEL  ((size_t)96924992)   // 1024
#define OFF_XTH0 ((size_t)96926016)
#define OFF_XTH1 ((size_t)100202816)
#define OFF_XTH2 ((size_t)106756416)
#define OFF_XTL0 ((size_t)119863616)
#define OFF_XTL1 ((size_t)123140416)
#define OFF_XTL2 ((size_t)129694016)
#define NEED_FULL ((size_t)142801216)
#define ZERO_U32  ((u32)166352)            // (262144+64+403200)/4, hist..logits

// weff/beff alias head of y0 (consumed by obj_conv); yw[256][1024] f32 also
// aliases y0 (zeroed by keys_kernel, AFTER obj_conv has consumed weff).
#define WEFF0_OFF (OFF_Y0)
#define WEFF1_OFF (OFF_Y0 + 110592)
#define WEFF2_OFF (OFF_Y0 + 165888)
#define BEFF_OFF  (OFF_Y0 + 193536)
#define WEFF_LEN  ((size_t)193600)
#define YW_OFF    (OFF_Y0)

// ---------------- bf16 helpers (RNE, finite inputs) ----------------
__device__ __forceinline__ short f2bf(float f) {
    u32 u = __float_as_uint(f);
    u = (u + 0x7fffu + ((u >> 16) & 1u)) >> 16;
    return (short)u;
}
__device__ __forceinline__ float bf2f(short h) {
    return __uint_as_float(((u32)(unsigned short)h) << 16);
}

// ---- weight prep (merged 3 heads + workspace zeroing) ----
// Fragment-ordered layout: [my(co/128)][ch(ci/32)][tap(9)][m(128)][ci(32)]
__global__ __launch_bounds__(256) void prep_w_all(
    const float* __restrict__ w0, short* __restrict__ wh0, short* __restrict__ wl0,
    const float* __restrict__ w1, short* __restrict__ wh1, short* __restrict__ wl1,
    const float* __restrict__ w2, short* __restrict__ wh2, short* __restrict__ wl2,
    u32* __restrict__ zbase)
{
    u32 b = blockIdx.x;
    if (b < 163) {
        u32 i = (b * 256 + threadIdx.x) * 4;
        if (i + 4 <= ZERO_U32) {
            *(uint4*)(zbase + i) = make_uint4(0u, 0u, 0u, 0u);
        } else {
            for (u32 k = i; k < ZERO_U32; ++k) zbase[k] = 0u;
        }
        return;
    }
    b -= 163;
    const float* w; short* wh; short* wl; int C;
    if (b < 4096)      { w = w0; wh = wh0; wl = wl0; C = 1024; }
    else if (b < 5120) { b -= 4096; w = w1; wh = wh1; wl = wl1; C = 512; }
    else               { b -= 5120; w = w2; wh = wh2; wl = wl2; C = 256; }

    __shared__ float ws_[2304];
    int chunks256 = C >> 8;
    int co = (int)b / chunks256;
    int ci0 = ((int)b % chunks256) << 8;
    size_t base = ((size_t)co * C + ci0) * 9;
    for (int idx = threadIdx.x; idx < 2304; idx += 256) ws_[idx] = w[base + idx];
    __syncthreads();
    int my = co >> 7, m = co & 127;
    int chunksW = C >> 5;
    for (int idx = threadIdx.x; idx < 2304; idx += 256) {
        int tap = idx >> 8, ci = idx & 255;
        float v = ws_[ci * 9 + tap];
        short h = f2bf(v);
        short l = f2bf(v - bf2f(h));
        int gci = ci0 + ci;
        int ch = gci >> 5, ciw = gci & 31;
        size_t o = ((((size_t)my * chunksW + ch) * 9 + tap) * 128 + m) * 32 + ciw;
        wh[o] = h; wl[o] = l;
    }
}

// ---- weff: pre-contract objectness 1x1 into the 3x3 conv ----
// R13: 672 blocks (co-split 32/16/8 -> each block reduces only 32 co),
// j-loop unrolled x4 (12 indep loads in flight). atomicAdd partials.
__global__ __launch_bounds__(256) void weff_kernel(
    const float* __restrict__ w30, const float* __restrict__ w1o0, const float* __restrict__ b30,
    const float* __restrict__ w31, const float* __restrict__ w1o1, const float* __restrict__ b31,
    const float* __restrict__ w32, const float* __restrict__ w1o2, const float* __restrict__ b32,
    float* __restrict__ weff0, float* __restrict__ weff1, float* __restrict__ weff2,
    float* __restrict__ beff)
{
    u32 b = blockIdx.x;
    const float *w3, *w1, *b3; float* wf; int C, hidx, splits;
    if (b < 512)      { w3 = w30; w1 = w1o0; b3 = b30; wf = weff0; C = 1024; hidx = 0; splits = 32; }
    else if (b < 640) { b -= 512; w3 = w31; w1 = w1o1; b3 = b31; wf = weff1; C = 512; hidx = 1; splits = 16; }
    else              { b -= 640; w3 = w32; w1 = w1o2; b3 = b32; wf = weff2; C = 256; hidx = 2; splits = 8; }
    int q = (int)b % splits, cib = (int)b / splits;
    int ci0 = cib * 64;
    int co0 = q * 32;          // cq = 32 for all heads

    __shared__ float lw1[3][32];
    __shared__ float bred[96];
    int t = threadIdx.x;
    if (t < 96) {
        int a = t >> 5, j = t & 31;
        lw1[a][j] = w1[(size_t)(a * 85 + 4) * C + co0 + j];
    }
    __syncthreads();

    float acc[3][3] = {};   // [pair][anchor]
    for (int j0 = 0; j0 < 32; j0 += 4) {
        float v[4][3];
        #pragma unroll
        for (int u = 0; u < 4; u++) {
            const float* row = w3 + ((size_t)(co0 + j0 + u) * C + ci0) * 9;
            #pragma unroll
            for (int pp = 0; pp < 3; pp++) {
                int pi = t + pp * 256;
                v[u][pp] = (pi < 576) ? row[pi] : 0.f;
            }
        }
        #pragma unroll
        for (int u = 0; u < 4; u++) {
            float l0 = lw1[0][j0 + u], l1 = lw1[1][j0 + u], l2 = lw1[2][j0 + u];
            #pragma unroll
            for (int pp = 0; pp < 3; pp++) {
                acc[pp][0] = fmaf(l0, v[u][pp], acc[pp][0]);
                acc[pp][1] = fmaf(l1, v[u][pp], acc[pp][1]);
                acc[pp][2] = fmaf(l2, v[u][pp], acc[pp][2]);
            }
        }
    }
    #pragma unroll
    for (int pp = 0; pp < 3; pp++) {
        int pi = t + pp * 256;
        if (pi < 576) {
            int cil = pi / 9, tap = pi - cil * 9;
            #pragma unroll
            for (int a = 0; a < 3; a++)
                atomicAdd(&wf[(size_t)(a * 9 + tap) * C + ci0 + cil], acc[pp][a]);
        }
    }
    if (cib == 0) {
        if (t < 96) {
            int a = t >> 5, j = t & 31;
            bred[t] = lw1[a][j] * b3[co0 + j];
        }
        __syncthreads();
        if (t < 3) {
            float s = 0.f;
            for (int j = 0; j < 32; j++) s += bred[t * 32 + j];
            atomicAdd(&beff[hidx * 3 + t], s);
        }
    }
}

// ---------------- input prep: [C][HW] f32 -> [pix][C] bf16 hi/lo (transpose) --
struct PrepX { const float* x; short* xh; short* xl; int C, HW, bbase, ptiles; };

__global__ __launch_bounds__(256) void prep_x_kernel(PrepX p0, PrepX p1, PrepX p2)
{
    PrepX p = (blockIdx.x >= (u32)p2.bbase) ? p2 :
              (blockIdx.x >= (u32)p1.bbase) ? p1 : p0;
    int local = blockIdx.x - p.bbase;
    int pt = local % p.ptiles, ct = local / p.ptiles;
    __shared__ short th[32][34];
    __shared__ short tl[32][34];
    for (int idx = threadIdx.x; idx < 1024; idx += 256) {
        int ci = idx >> 5, px = idx & 31;
        float v = p.x[(size_t)(ct * 32 + ci) * p.HW + pt * 32 + px];
        short h = f2bf(v);
        th[ci][px] = h;
        tl[ci][px] = f2bf(v - bf2f(h));
    }
    __syncthreads();
    for (int idx = threadIdx.x; idx < 1024; idx += 256) {
        int px = idx >> 5, ci = idx & 31;
        size_t o = (size_t)(pt * 32 + px) * p.C + ct * 32 + ci;
        p.xh[o] = th[ci][px];
        p.xl[o] = tl[ci][px];
    }
}

// ---- obj conv: 3-out-channel 3x3 conv (fp32 VALU) -> logits atomicAdd ----
struct ObjHead { const float* x; const float* wf; int C, H, W, HW, splits, lbase, bbase; };

__global__ __launch_bounds__(256) void obj_conv(
    ObjHead o0, ObjHead o1, ObjHead o2, const float* __restrict__ beff,
    float* __restrict__ logits)
{
    ObjHead oh; int hidx;
    if (blockIdx.x >= (u32)o2.bbase)      { oh = o2; hidx = 2; }
    else if (blockIdx.x >= (u32)o1.bbase) { oh = o1; hidx = 1; }
    else                                  { oh = o0; hidx = 0; }
    int local = blockIdx.x - oh.bbase;
    int cib = local % oh.splits;
    int pt  = local / oh.splits;
    int ci0 = cib * 32;

    __shared__ float wf[27][32];   // [a*9+tap][ci]
    for (int idx = threadIdx.x; idx < 864; idx += 256) {
        int at = idx >> 5, ci = idx & 31;
        wf[at][ci] = oh.wf[(size_t)at * oh.C + ci0 + ci];
    }
    __syncthreads();

    int p = pt * 256 + threadIdx.x;
    if (p >= oh.HW) return;
    int py = p / oh.W, px = p - py * oh.W;

    int xoff[9];
    #pragma unroll
    for (int t9 = 0; t9 < 9; t9++) {
        int dy = t9 / 3 - 1, dx = t9 % 3 - 1;
        int gy = py + dy, gx = px + dx;
        xoff[t9] = (gy >= 0 && gy < oh.H && gx >= 0 && gx < oh.W) ? (gy * oh.W + gx) : -1;
    }
    float a0, a1, a2;
    if (cib == 0) { a0 = beff[hidx*3]; a1 = beff[hidx*3+1]; a2 = beff[hidx*3+2]; }
    else          { a0 = a1 = a2 = 0.f; }
    const float* xr = oh.x + (size_t)ci0 * oh.HW;
    for (int ci = 0; ci < 32; ci++) {
        const float* xc = xr + (size_t)ci * oh.HW;
        #pragma unroll
        for (int t9 = 0; t9 < 9; t9++) {
            int o = xoff[t9];
            float xv = (o >= 0) ? xc[o] : 0.f;
            a0 = fmaf(wf[t9][ci],      xv, a0);
            a1 = fmaf(wf[9 + t9][ci],  xv, a1);
            a2 = fmaf(wf[18 + t9][ci], xv, a2);
        }
    }
    atomicAdd(&logits[oh.lbase + p], a0);
    atomicAdd(&logits[oh.lbase + oh.HW + p], a1);
    atomicAdd(&logits[oh.lbase + 2 * oh.HW + p], a2);
}

// ---------------- keys + yw zeroing ----------------
__global__ __launch_bounds__(256) void keys_kernel(
    const float* __restrict__ logits,
    const float* __restrict__ b10, const float* __restrict__ b11, const float* __restrict__ b12,
    u64* __restrict__ keys, u32* __restrict__ hist, float* __restrict__ yw)
{
    u32 gi = blockIdx.x * 256 + threadIdx.x;
    if (gi < 65536u) ((uint4*)yw)[gi] = make_uint4(0u, 0u, 0u, 0u);  // 1MB yw zero
    int i = (int)gi;
    if (i >= NBOX) return;
    float bias;
    if (i < 4800)       bias = b10[(i / 1600) * 85 + 4];
    else if (i < 24000) bias = b11[((i - 4800) / 6400) * 85 + 4];
    else                bias = b12[((i - 24000) / 25600) * 85 + 4];
    float s = 1.0f / (1.0f + expf(-(logits[i] + bias)));
    u64 k = ((u64)__float_as_uint(s) << 32) | (u64)(0xFFFFFFFFu - (u32)i);
    keys[i] = k;
    atomicAdd(&hist[(u32)(k >> 48)], 1u);
}

// ---------------- top-256 selection ----------------
__global__ __launch_bounds__(256) void select_kernel(const u32* __restrict__ hist,
                                                     u32* __restrict__ meta)
{
    __shared__ u32 csum[256];
    int t = threadIdx.x;
    const uint4* h4 = (const uint4*)(hist + t * 256);
    u32 s = 0;
    #pragma unroll 8
    for (int i = 0; i < 64; i++) { uint4 v = h4[i]; s += v.x + v.y + v.z + v.w; }
    csum[t] = s;
    __syncthreads();
    if (t == 0) {
        u32 cum = 0; int chunk = 255;
        for (; chunk > 0; chunk--) {
            if (cum + csum[chunk] >= 256u) break;
            cum += csum[chunk];
        }
        int B = chunk * 256;
        u32 cumAbove = cum;
        for (int bb = chunk * 256 + 255; bb >= chunk * 256; bb--) {
            u32 h = hist[bb];
            if (cumAbove + h >= 256u) { B = bb; break; }
            cumAbove += h;
        }
        meta[0] = (u32)B;
        meta[1] = cumAbove;
    }
}

__global__ __launch_bounds__(256) void compact_kernel(
    const u64* __restrict__ keys, int n, const u32* __restrict__ meta,
    u64* __restrict__ cand, u32* __restrict__ count)
{
    int i = blockIdx.x * blockDim.x + threadIdx.x;
    if (i < n) {
        u64 k = keys[i];
        if ((u32)(k >> 48) >= meta[0]) {
            u32 pos = atomicAdd(count, 1u);
            if (pos < CAND_CAP) cand[pos] = k;
        }
    }
}

// Dynamic bitonic sort; epilogue: head-partitioned selp + selr (rank map).
__global__ __launch_bounds__(1024) void sort_select_kernel(
    const u64* __restrict__ cand, const u32* __restrict__ meta,
    u32* __restrict__ sel, u32* __restrict__ selp, u32* __restrict__ selr,
    u32* __restrict__ cnts)
{
    __shared__ u64 sk[CAND_CAP];
    __shared__ u32 selw[256];
    __shared__ unsigned char hh[256];
    int n = (int)meta[2];
    if (n > CAND_CAP) n = CAND_CAP;
    int P = 256;
    while (P < n) P <<= 1;          // 256 <= P <= 4096, uniform across block
    for (int i = threadIdx.x; i < P; i += 1024)
        sk[i] = (i < n) ? cand[i] : 0ull;
    __syncthreads();
    for (int k = 2; k <= P; k <<= 1) {
        for (int j = k >> 1; j > 0; j >>= 1) {
            for (int i = threadIdx.x; i < P; i += 1024) {
                int ixj = i ^ j;
                if (ixj > i) {
                    u64 a = sk[i], c = sk[ixj];
                    bool sw = ((i & k) == 0) ? (a > c) : (a < c);
                    if (sw) { sk[i] = c; sk[ixj] = a; }
                }
            }
            __syncthreads();
        }
    }
    if (threadIdx.x < 256) {
        u64 k = sk[P - 1 - threadIdx.x];
        u32 bi = 0xFFFFFFFFu - (u32)(k & 0xFFFFFFFFull);
        sel[threadIdx.x] = bi;
        selw[threadIdx.x] = bi;
        hh[threadIdx.x] = bi < 4800u ? 0 : (bi < 24000u ? 1 : 2);
    }
    __syncthreads();
    if (threadIdx.x < 256) {
        int h = hh[threadIdx.x];
        int rank = 0, n0 = 0, n1 = 0;
        for (int j = 0; j < 256; j++) {
            int hj = hh[j];
            if (j < (int)threadIdx.x && hj == h) rank++;
            if (hj == 0) n0++; else if (hj == 1) n1++;
        }
        int base = (h == 0) ? 0 : (h == 1) ? n0 : n0 + n1;
        selp[base + rank] = selw[threadIdx.x];
        selr[base + rank] = threadIdx.x;
        if (threadIdx.x == 0) { cnts[0] = (u32)n0; cnts[1] = (u32)n1; }
    }
}

// ---- winner GEMM: full C-channel 3x3 conv at the <=256 winner pixels ----
// R13: K-split 4/2/1 (uniform 8 chunks x 9 taps = 72 iters/block), 576 blocks.
// Output: compact yw[rank][1024] via atomicAdd (pre-zeroed); bias by kb==0.
struct WinHead {
    const short* wh; const short* wl; const short* xh; const short* xl;
    const float* xf; const float* bias;
    int C, H, W, HW, mycnt, ksplit, hbase;
};

__global__ __launch_bounds__(256) void winner_gemm(
    WinHead g0, WinHead g1, WinHead g2,
    const u32* __restrict__ selp, const u32* __restrict__ selr,
    const u32* __restrict__ cnts, float* __restrict__ yw, int use_xt)
{
    const u32 c0 = cnts[0], c1 = cnts[1];
    const u32 c2 = 256u - c0 - c1;
    const int ng0 = (int)((c0 + 15) >> 4), ng1 = (int)((c1 + 15) >> 4), ng2 = (int)((c2 + 15) >> 4);
    const int grpIdx = blockIdx.x >> 5;      // 8 my x 4 kb = 32
    const int my = (blockIdx.x >> 2) & 7;
    const int kb = blockIdx.x & 3;
    WinHead g; int gl, spbase; u32 hcnt;
    if (grpIdx < ng0)            { gl = grpIdx;            g = g0; spbase = gl * 16;                  hcnt = c0; }
    else if (grpIdx < ng0 + ng1) { gl = grpIdx - ng0;      g = g1; spbase = (int)c0 + gl * 16;        hcnt = c1; }
    else { gl = grpIdx - ng0 - ng1; if (gl >= ng2) return; g = g2; spbase = (int)(c0 + c1) + gl * 16; hcnt = c2; }
    if (my >= g.mycnt || kb >= g.ksplit) return;
    const int vcnt = min(16, (int)hcnt - gl * 16);

    const int tid = threadIdx.x;
    const int lane = tid & 63;
    const int wave = tid >> 6;
    const int quad = lane >> 4;
    const int l15 = lane & 15;

    __shared__ int o_lds[16][9];
    __shared__ int r_lds[16];
    if (tid < 144) {
        int n = tid / 9, tap = tid - n * 9;
        int o = -1;
        if (n < vcnt) {
            u32 bi = selp[spbase + n];
            int r = (int)bi - g.hbase;
            int p = r % g.HW;
            int py = p / g.W, px = p - py * g.W;
            int dy = tap / 3 - 1, dx = tap % 3 - 1;
            int gy = py + dy, gx = px + dx;
            if (gy >= 0 && gy < g.H && gx >= 0 && gx < g.W) o = gy * g.W + gx;
        }
        o_lds[n][tap] = o;
        if (tap == 0) r_lds[n] = (n < vcnt) ? (int)selr[spbase + n] : -1;
    }
    __syncthreads();
    int otap[9];
    #pragma unroll
    for (int t9 = 0; t9 < 9; t9++) otap[t9] = o_lds[l15][t9];
    const int rk = r_lds[l15];

    const int chunksAll = g.C >> 5;
    const int myChunks = chunksAll / g.ksplit;   // 8 for all heads
    const int ch0 = kb * myChunks;
    const int f0 = wave * 2;
    const size_t abase = (size_t)my * chunksAll * 9 * 4096 + f0 * 512 + l15 * 32 + quad * 8;
    const short* __restrict__ wAh = g.wh + abase;
    const short* __restrict__ wAl = g.wl + abase;

    f32x4 acc0 = (f32x4){0.f,0.f,0.f,0.f}, acc1 = (f32x4){0.f,0.f,0.f,0.f};
    for (int cc = 0; cc < myChunks; ++cc) {
        const int ch = ch0 + cc;
        const int ci0 = ch << 5;
        #pragma unroll
        for (int tap = 0; tap < 9; ++tap) {
            size_t soff = ((size_t)ch * 9 + tap) * 4096;
            short8 a0h = *(const short8*)(wAh + soff);
            short8 a1h = *(const short8*)(wAh + soff + 512);
            short8 a0l = *(const short8*)(wAl + soff);
            short8 a1l = *(const short8*)(wAl + soff + 512);
            short8 bh = (short8){0,0,0,0,0,0,0,0};
            short8 bl = (short8){0,0,0,0,0,0,0,0};
            int o = otap[tap];
            if (o >= 0) {
                if (use_xt) {
                    size_t ro = (size_t)o * g.C + ci0 + quad * 8;
                    bh = *(const short8*)(g.xh + ro);
                    bl = *(const short8*)(g.xl + ro);
                } else {
                    #pragma unroll
                    for (int k = 0; k < 8; k++) {
                        float xv = g.xf[(size_t)(ci0 + quad * 8 + k) * g.HW + o];
                        short hh2 = f2bf(xv);
                        bh[k] = hh2; bl[k] = f2bf(xv - bf2f(hh2));
                    }
                }
            }
            acc0 = __builtin_amdgcn_mfma_f32_16x16x32_bf16(a0h, bh, acc0, 0, 0, 0);
            acc1 = __builtin_amdgcn_mfma_f32_16x16x32_bf16(a1h, bh, acc1, 0, 0, 0);
            acc0 = __builtin_amdgcn_mfma_f32_16x16x32_bf16(a0l, bh, acc0, 0, 0, 0);
            acc1 = __builtin_amdgcn_mfma_f32_16x16x32_bf16(a1l, bh, acc1, 0, 0, 0);
            acc0 = __builtin_amdgcn_mfma_f32_16x16x32_bf16(a0h, bl, acc0, 0, 0, 0);
            acc1 = __builtin_amdgcn_mfma_f32_16x16x32_bf16(a1h, bl, acc1, 0, 0, 0);
        }
    }
    if (rk >= 0) {
        #pragma unroll
        for (int r = 0; r < 4; r++) {
            int coA = my * 128 + f0 * 16 + quad * 4 + r;
            float vA = acc0[r] + (kb == 0 ? g.bias[coA] : 0.f);
            atomicAdd(&yw[(size_t)rk * 1024 + coA], vA);
            int coB = coA + 16;
            float vB = acc1[r] + (kb == 0 ? g.bias[coB] : 0.f);
            atomicAdd(&yw[(size_t)rk * 1024 + coB], vB);
        }
    }
}

// ---------------- final: full 85-ch 1x1 conv + decode for the 256 winners ---
// R13: reads compact yw[rank][1024] (contiguous) instead of stride-HW y.
__global__ __launch_bounds__(256) void final_kernel(
    const float* __restrict__ yw,
    const float* __restrict__ w10, const float* __restrict__ w11, const float* __restrict__ w12,
    const float* __restrict__ b10, const float* __restrict__ b11, const float* __restrict__ b12,
    const u32* __restrict__ sel, float* __restrict__ out)
{
    int b = blockIdx.x;
    u32 bi = sel[b];
    const float *w1, *b1;
    int C, H, W, base; float ratio;
    float anchs[6];
    if (bi < 4800u) {
        w1 = w10; b1 = b10; C = 1024; H = 40; W = 40; base = 0; ratio = 32.f;
        anchs[0]=116.f; anchs[1]=90.f; anchs[2]=156.f; anchs[3]=198.f; anchs[4]=373.f; anchs[5]=326.f;
    } else if (bi < 24000u) {
        w1 = w11; b1 = b11; C = 512; H = 80; W = 80; base = 4800; ratio = 16.f;
        anchs[0]=30.f; anchs[1]=61.f; anchs[2]=62.f; anchs[3]=45.f; anchs[4]=59.f; anchs[5]=119.f;
    } else {
        w1 = w12; b1 = b12; C = 256; H = 160; W = 160; base = 24000; ratio = 8.f;
        anchs[0]=10.f; anchs[1]=13.f; anchs[2]=16.f; anchs[3]=30.f; anchs[4]=33.f; anchs[5]=23.f;
    }
    int HW = H * W;
    int r = (int)bi - base;
    int a = r / HW, p = r % HW;
    __shared__ float ys[256];
    int c = threadIdx.x;
    float acc = 0.f;
    const float* wrow = w1 + (size_t)(a * 85 + (c < 85 ? c : 0)) * C;
    const float* yrow = yw + (size_t)b * 1024;
    for (int ci0 = 0; ci0 < C; ci0 += 256) {
        __syncthreads();
        ys[c] = yrow[ci0 + c];
        __syncthreads();
        if (c < 85)
            for (int ci = 0; ci < 256; ci++) acc = fmaf(ys[ci], wrow[ci0 + ci], acc);
    }
    if (c < 85) {
        float v = acc + b1[a * 85 + c];
        float s = 1.0f / (1.0f + expf(-v));
        int py = p / W, px = p - (p / W) * W;
        float o;
        if (c == 0)      o = (s * 2.0f - 0.5f + (float)px) * ratio;
        else if (c == 1) o = (s * 2.0f - 0.5f + (float)py) * ratio;
        else if (c == 2) { float t = s * 2.0f; o = t * t * anchs[a * 2]; }
        else if (c == 3) { float t = s * 2.0f; o = t * t * anchs[a * 2 + 1]; }
        else             o = s;
        out[(size_t)b * 85 + c] = o;
    }
}

// ---------------- launch ----------------
extern "C" void kernel_launch(void* const* d_in, const int* in_sizes, int n_in,
                              void* d_out, int out_size, void* d_ws, size_t ws_size,
                              hipStream_t stream)
{
    const float* feat0 = (const float*)d_in[0];   // (256,160,160)
    const float* feat1 = (const float*)d_in[1];   // (512,80,80)
    const float* feat2 = (const float*)d_in[2];   // (1024,40,40)
    const float* w3_0 = (const float*)d_in[3];  const float* b3_0 = (const float*)d_in[4];
    const float* w1_0 = (const float*)d_in[5];  const float* b1_0 = (const float*)d_in[6];
    const float* w3_1 = (const float*)d_in[7];  const float* b3_1 = (const float*)d_in[8];
    const float* w1_1 = (const float*)d_in[9];  const float* b1_1 = (const float*)d_in[10];
    const float* w3_2 = (const float*)d_in[11]; const float* b3_2 = (const float*)d_in[12];
    const float* w1_2 = (const float*)d_in[13]; const float* b1_2 = (const float*)d_in[14];

    char* ws = (char*)d_ws;
    short* wth0 = (short*)(ws + OFF_WTH0);
    short* wth1 = (short*)(ws + OFF_WTH1);
    short* wth2 = (short*)(ws + OFF_WTH2);
    short* wtl0 = (short*)(ws + OFF_WTL0);
    short* wtl1 = (short*)(ws + OFF_WTL1);
    short* wtl2 = (short*)(ws + OFF_WTL2);
    u64*   keys = (u64*)  (ws + OFF_KEYS);
    u32*   hist = (u32*)  (ws + OFF_HIST);
    u32*   meta = (u32*)  (ws + OFF_META);
    float* logits = (float*)(ws + OFF_LOG);
    u64*   cand = (u64*)  (ws + OFF_CAND);
    u32*   sel  = (u32*)  (ws + OFF_SEL);
    float* weff0 = (float*)(ws + WEFF0_OFF);
    float* weff1 = (float*)(ws + WEFF1_OFF);
    float* weff2 = (float*)(ws + WEFF2_OFF);
    float* beff  = (float*)(ws + BEFF_OFF);
    float* yw    = (float*)(ws + YW_OFF);

    const int use_xt = (ws_size >= NEED_FULL) ? 1 : 0;
    short* xth0 = (short*)(ws + OFF_XTH0);
    short* xth1 = (short*)(ws + OFF_XTH1);
    short* xth2 = (short*)(ws + OFF_XTH2);
    short* xtl0 = (short*)(ws + OFF_XTL0);
    short* xtl1 = (short*)(ws + OFF_XTL1);
    short* xtl2 = (short*)(ws + OFF_XTL2);

    // weff/beff zero (aliases head of y0; consumed by obj_conv before yw reuse)
    hipMemsetAsync(ws + OFF_Y0, 0, WEFF_LEN, stream);

    // weight transforms (fragment-ordered) + hist/meta/logits zeroing
    prep_w_all<<<163 + 4096 + 1024 + 256, 256, 0, stream>>>(
        w3_0, wth0, wtl0, w3_1, wth1, wtl1, w3_2, wth2, wtl2, (u32*)(ws + OFF_HIST));

    // objectness weight pre-contraction (672 blocks, 32-co reductions)
    weff_kernel<<<672, 256, 0, stream>>>(w3_0, w1_0, b3_0, w3_1, w1_1, b3_1,
                                         w3_2, w1_2, b3_2, weff0, weff1, weff2, beff);

    // input transpose + bf16 split (feeds winner_gemm B gathers)
    if (use_xt) {
        PrepX p0 = {feat2, xth0, xtl0, 1024, 1600,  0,    50};
        PrepX p1 = {feat1, xth1, xtl1, 512,  6400,  1600, 200};
        PrepX p2 = {feat0, xth2, xtl2, 256,  25600, 4800, 800};
        prep_x_kernel<<<11200, 256, 0, stream>>>(p0, p1, p2);
    }

    // objectness logits for all boxes (3-channel conv, fp32)
    ObjHead o0 = {feat2, weff0, 1024, 40,  40,  1600,  32, 0,     0};
    ObjHead o1 = {feat1, weff1, 512,  80,  80,  6400,  16, 4800,  224};
    ObjHead o2 = {feat0, weff2, 256,  160, 160, 25600, 8,  24000, 624};
    obj_conv<<<1424, 256, 0, stream>>>(o0, o1, o2, beff, logits);

    // keys + histogram from logits (+ yw zeroing; obj_conv already consumed weff)
    keys_kernel<<<(NBOX + 255) / 256, 256, 0, stream>>>(logits, b1_0, b1_1, b1_2,
                                                        keys, hist, yw);

    // top-256
    select_kernel<<<1, 256, 0, stream>>>(hist, meta);
    compact_kernel<<<(NBOX + 255) / 256, 256, 0, stream>>>(keys, NBOX, meta, cand, meta + 2);
    u32* selp = (u32*)(ws + OFF_HIST);
    u32* selr = selp + 256;
    sort_select_kernel<<<1, 1024, 0, stream>>>(cand, meta, sel, selp, selr, meta + 4);

    // full-C conv at winner pixels only -> compact yw[rank][1024]
    WinHead g0 = {wth0, wtl0, xth0, xtl0, feat2, b3_0, 1024, 40,  40,  1600,  8, 4, 0};
    WinHead g1 = {wth1, wtl1, xth1, xtl1, feat1, b3_1, 512,  80,  80,  6400,  4, 2, 4800};
    WinHead g2 = {wth2, wtl2, xth2, xtl2, feat0, b3_2, 256,  160, 160, 25600, 2, 1, 24000};
    winner_gemm<<<576, 256, 0, stream>>>(g0, g1, g2, selp, selr, meta + 4, yw, use_xt);

    // full 85-channel compute + decode for winners only
    final_kernel<<<256, 256, 0, stream>>>(yw, w1_0, w1_1, w1_2,
                                          b1_0, b1_1, b1_2, sel, (float*)d_out);
}